// Round 1
// baseline (20710.239 us; speedup 1.0000x reference)
//
#include <hip/hip_runtime.h>

#define N_ALL 20000
#define NPCD  5000
#define NRGB  15000
#define CPCD  32
#define CRGB  128
#define CF    160
#define NA    4096
#define SANS  32
#define NBK   64
#define K1    163
#define K1P   168
#define HD    128
#define FPK   288

// ---------------- prep: build xyz(20000x3), feat(20000x160), padded sa_W1(128x168) ----------------
__global__ void prep_kernel(const float* __restrict__ pcd_xyz,
                            const float* __restrict__ pcd_feat,
                            const float* __restrict__ rgb_xyz,
                            const float* __restrict__ rgb_feat,
                            const float* __restrict__ sa_W1,
                            float* __restrict__ xyz,
                            float* __restrict__ feat,
                            float* __restrict__ W1p) {
  const int TOT = N_ALL*CF + N_ALL*3 + HD*K1P;
  for (int id = blockIdx.x*blockDim.x + threadIdx.x; id < TOT; id += gridDim.x*blockDim.x) {
    if (id < N_ALL*CF) {
      int r = id / CF, c = id - r*CF;
      float v = 0.0f;
      if (r < NPCD) { if (c < CPCD) v = pcd_feat[r*CPCD + c]; }
      else          { if (c >= CPCD) v = rgb_feat[(c - CPCD)*NRGB + (r - NPCD)]; }
      feat[id] = v;
    } else if (id < N_ALL*CF + N_ALL*3) {
      int e = id - N_ALL*CF;
      xyz[e] = (e < NPCD*3) ? pcd_xyz[e] : rgb_xyz[e - NPCD*3];
    } else {
      int e = id - (N_ALL*CF + N_ALL*3);
      int o = e / K1P, c = e - o*K1P;
      W1p[e] = (c < K1) ? sa_W1[o*K1 + c] : 0.0f;
    }
  }
}

// ---------------- FPS: single block, coords+dists in registers ----------------
__global__ void __launch_bounds__(1024) fps_kernel(const float* __restrict__ xyz,
                                                   int* __restrict__ fidx,
                                                   float* __restrict__ axyz) {
  #pragma clang fp contract(off)
  const int t = threadIdx.x;
  float xs[20], ys[20], zs[20], ds[20];
  #pragma unroll
  for (int i = 0; i < 20; i++) {
    int p = t + (i << 10);
    if (p < N_ALL) { xs[i]=xyz[3*p]; ys[i]=xyz[3*p+1]; zs[i]=xyz[3*p+2]; ds[i]=1e10f; }
    else           { xs[i]=0.0f; ys[i]=0.0f; zs[i]=0.0f; ds[i]=-1.0f; } // pad never wins (real dists >= 0)
  }
  __shared__ unsigned long long red16[16];
  __shared__ float cs[3];
  float cx = xyz[0], cy = xyz[1], cz = xyz[2];
  if (t == 0) { fidx[0] = 0; axyz[0] = cx; axyz[1] = cy; axyz[2] = cz; }
  const int lane = t & 63, wv = t >> 6;
  for (int it = 1; it < NA; ++it) {
    float bd = -1e30f; int bi = 0;
    #pragma unroll
    for (int i = 0; i < 20; i++) {
      float dx = xs[i]-cx, dy = ys[i]-cy, dz = zs[i]-cz;
      float d  = (dx*dx + dy*dy) + dz*dz;     // plain f32, no contraction
      float nd = fminf(ds[i], d);
      ds[i] = nd;
      if (nd > bd) { bd = nd; bi = i; }       // ascending i => lowest index on ties
    }
    unsigned long long pk =
      ((unsigned long long)__float_as_uint(bd) << 32) | (unsigned)(~((bi << 10) + t));
    #pragma unroll
    for (int off = 1; off < 64; off <<= 1) {
      unsigned long long o = __shfl_xor(pk, off);
      pk = (o > pk) ? o : pk;
    }
    if (lane == 0) red16[wv] = pk;
    __syncthreads();
    unsigned long long m = red16[0];
    #pragma unroll
    for (int w = 1; w < 16; w++) { unsigned long long o = red16[w]; m = (o > m) ? o : m; }
    unsigned gi = ~(unsigned)(m & 0xFFFFFFFFu);
    if ((gi & 1023u) == (unsigned)t) {
      int i = gi >> 10;
      cs[0]=xs[i]; cs[1]=ys[i]; cs[2]=zs[i];
      fidx[it] = (int)gi;
      axyz[3*it]=xs[i]; axyz[3*it+1]=ys[i]; axyz[3*it+2]=zs[i];
    }
    __syncthreads();
    cx = cs[0]; cy = cs[1]; cz = cs[2];
  }
}

// ---------------- ball query (wave per center): first K smallest indices with d2 < r2 ----------------
__global__ void sa_bq_kernel(const float* __restrict__ xyz,
                             const float* __restrict__ axyz,
                             int* __restrict__ nb) {
  #pragma clang fp contract(off)
  int wv = threadIdx.x >> 6, lane = threadIdx.x & 63;
  int a = blockIdx.x*4 + wv;
  float ax = axyz[3*a], ay = axyz[3*a+1], az = axyz[3*a+2];
  int cnt = 0, my = 0;
  for (int base = 0; base < N_ALL; base += 64) {
    int p = base + lane;
    bool in = false;
    if (p < N_ALL) {
      float dx = ax - xyz[3*p], dy = ay - xyz[3*p+1], dz = az - xyz[3*p+2];
      float d2 = (dx*dx + dy*dy) + dz*dz;
      in = d2 < 0.01f;
    }
    unsigned long long mask = __ballot(in);
    while (mask && cnt < SANS) {
      int b = __builtin_ctzll(mask);
      mask &= mask - 1;
      if (cnt == lane) my = base + b;
      cnt++;
    }
    if (cnt >= SANS) break;
  }
  int f0 = __shfl(my, 0);
  if (lane < SANS) nb[a*SANS + lane] = (lane < cnt) ? my : f0;
}

__global__ void det_bq_kernel(const float* __restrict__ pxyz,
                              int* __restrict__ nb) {
  #pragma clang fp contract(off)
  int wv = threadIdx.x >> 6, lane = threadIdx.x & 63;
  int i = blockIdx.x*4 + wv;
  float ax = pxyz[3*i], ay = pxyz[3*i+1], az = pxyz[3*i+2];
  int cnt = 0, my = 0;
  for (int base = 0; base < NPCD; base += 64) {
    int p = base + lane;
    bool in = false;
    if (p < NPCD) {
      float dx = ax - pxyz[3*p], dy = ay - pxyz[3*p+1], dz = az - pxyz[3*p+2];
      float d2 = (dx*dx + dy*dy) + dz*dz;
      in = d2 < 0.04f;
    }
    unsigned long long mask = __ballot(in);
    while (mask && cnt < NBK) {
      int b = __builtin_ctzll(mask);
      mask &= mask - 1;
      if (cnt == lane) my = base + b;
      cnt++;
    }
    if (cnt >= NBK) break;
  }
  int f0 = __shfl(my, 0);
  nb[i*NBK + lane] = (lane < cnt) ? my : f0;
}

// ---------------- SA: gather g(32x163) -> 3x MLP(128) -> maxpool, one anchor per block ----------------
__global__ void __launch_bounds__(128) sa_mlp_kernel(const float* __restrict__ xyz,
                                                     const float* __restrict__ feat,
                                                     const float* __restrict__ axyz,
                                                     const int* __restrict__ nb,
                                                     const float* __restrict__ W1p,
                                                     const float* __restrict__ b1,
                                                     const float* __restrict__ W2,
                                                     const float* __restrict__ b2,
                                                     const float* __restrict__ W3,
                                                     const float* __restrict__ b3,
                                                     float* __restrict__ sa_feat) {
  __shared__ float g[SANS*K1P];     // 21504 B, reused as h2
  __shared__ float h1[SANS*HD];     // 16384 B
  __shared__ int nbs[SANS];
  int a = blockIdx.x, tid = threadIdx.x;
  if (tid < SANS) nbs[tid] = nb[a*SANS + tid];
  float ax = axyz[3*a], ay = axyz[3*a+1], az = axyz[3*a+2];
  __syncthreads();
  for (int e = tid; e < SANS*K1P; e += 128) {
    int s = e / K1P, c = e - s*K1P;
    float v = 0.0f;
    int p = nbs[s];
    if (c < 3) {
      float pc  = xyz[3*p + c];
      float acx = (c == 0) ? ax : ((c == 1) ? ay : az);
      v = (pc - acx) / 0.1f;
    } else if (c < K1) {
      v = feat[p*CF + (c - 3)];
    }
    g[e] = v;
  }
  __syncthreads();
  const int o = tid;
  float acc[SANS];
  // layer 1: K = 168 (zero padded)
  #pragma unroll
  for (int s = 0; s < SANS; s++) acc[s] = b1[o];
  for (int kc = 0; kc < 21; kc++) {
    const float4* wp = (const float4*)(W1p + o*K1P + kc*8);
    float4 w0 = wp[0], w1 = wp[1];
    #pragma unroll
    for (int s = 0; s < SANS; s++) {
      const float4* gp = (const float4*)(g + s*K1P + kc*8);
      float4 g0 = gp[0], g1 = gp[1];
      acc[s] += w0.x*g0.x + w0.y*g0.y + w0.z*g0.z + w0.w*g0.w
              + w1.x*g1.x + w1.y*g1.y + w1.z*g1.z + w1.w*g1.w;
    }
  }
  #pragma unroll
  for (int s = 0; s < SANS; s++) h1[s*HD + o] = fmaxf(acc[s], 0.0f);
  __syncthreads();
  // layer 2: K = 128, write h2 into g buffer
  #pragma unroll
  for (int s = 0; s < SANS; s++) acc[s] = b2[o];
  for (int kc = 0; kc < 16; kc++) {
    const float4* wp = (const float4*)(W2 + o*HD + kc*8);
    float4 w0 = wp[0], w1 = wp[1];
    #pragma unroll
    for (int s = 0; s < SANS; s++) {
      const float4* gp = (const float4*)(h1 + s*HD + kc*8);
      float4 g0 = gp[0], g1 = gp[1];
      acc[s] += w0.x*g0.x + w0.y*g0.y + w0.z*g0.z + w0.w*g0.w
              + w1.x*g1.x + w1.y*g1.y + w1.z*g1.z + w1.w*g1.w;
    }
  }
  float* h2 = g;
  #pragma unroll
  for (int s = 0; s < SANS; s++) h2[s*HD + o] = fmaxf(acc[s], 0.0f);
  __syncthreads();
  // layer 3 + max pool
  #pragma unroll
  for (int s = 0; s < SANS; s++) acc[s] = b3[o];
  for (int kc = 0; kc < 16; kc++) {
    const float4* wp = (const float4*)(W3 + o*HD + kc*8);
    float4 w0 = wp[0], w1 = wp[1];
    #pragma unroll
    for (int s = 0; s < SANS; s++) {
      const float4* gp = (const float4*)(h2 + s*HD + kc*8);
      float4 g0 = gp[0], g1 = gp[1];
      acc[s] += w0.x*g0.x + w0.y*g0.y + w0.z*g0.z + w0.w*g0.w
              + w1.x*g1.x + w1.y*g1.y + w1.z*g1.z + w1.w*g1.w;
    }
  }
  float m = 0.0f;
  #pragma unroll
  for (int s = 0; s < SANS; s++) m = fmaxf(m, fmaxf(acc[s], 0.0f));
  sa_feat[a*HD + o] = m;
}

// ---------------- 3-NN interp (first 5000 points only) + build F row [interp(128)|feat(160)] ----------------
#define INSERT3(v) { if ((v) < t0){ t2=t1; t1=t0; t0=(v);} \
                     else if ((v) < t1){ t2=t1; t1=(v);} \
                     else if ((v) < t2){ t2=(v);} }

__global__ void nn_interp_kernel(const float* __restrict__ xyz,
                                 const float* __restrict__ feat,
                                 const float* __restrict__ axyz,
                                 const float* __restrict__ sa_feat,
                                 float* __restrict__ F) {
  #pragma clang fp contract(off)
  int wv = threadIdx.x >> 6, lane = threadIdx.x & 63;
  int p = blockIdx.x*4 + wv;
  float px = xyz[3*p], py = xyz[3*p+1], pz = xyz[3*p+2];
  unsigned long long t0 = ~0ull, t1 = ~0ull, t2 = ~0ull;
  for (int j = 0; j < 64; j++) {
    int a = lane + (j << 6);
    float dx = px - axyz[3*a], dy = py - axyz[3*a+1], dz = pz - axyz[3*a+2];
    float d2 = (dx*dx + dy*dy) + dz*dz;
    unsigned long long pk = ((unsigned long long)__float_as_uint(d2) << 32) | (unsigned)a;
    INSERT3(pk);
  }
  #pragma unroll
  for (int off = 1; off < 64; off <<= 1) {
    unsigned long long b0 = __shfl_xor(t0, off);
    unsigned long long b1 = __shfl_xor(t1, off);
    unsigned long long b2 = __shfl_xor(t2, off);
    INSERT3(b0); INSERT3(b1); INSERT3(b2);
  }
  float d0 = __uint_as_float((unsigned)(t0 >> 32));
  float d1 = __uint_as_float((unsigned)(t1 >> 32));
  float d2v = __uint_as_float((unsigned)(t2 >> 32));
  int a0 = (int)(t0 & 0xFFFFFFFFull), a1 = (int)(t1 & 0xFFFFFFFFull), a2 = (int)(t2 & 0xFFFFFFFFull);
  float w0 = 1.0f/(d0 + 1e-8f), w1 = 1.0f/(d1 + 1e-8f), w2 = 1.0f/(d2v + 1e-8f);
  float wsum = w0 + w1 + w2;
  w0 /= wsum; w1 /= wsum; w2 /= wsum;
  const float* s0 = sa_feat + a0*HD;
  const float* s1 = sa_feat + a1*HD;
  const float* s2 = sa_feat + a2*HD;
  float* Fr = F + p*FPK;
  Fr[lane]      = w0*s0[lane]    + w1*s1[lane]    + w2*s2[lane];
  Fr[lane + 64] = w0*s0[lane+64] + w1*s1[lane+64] + w2*s2[lane+64];
  const float* fr = feat + p*CF;
  Fr[HD + lane]      = fr[lane];
  Fr[HD + lane + 64] = fr[lane + 64];
  if (lane < 32) Fr[HD + 128 + lane] = fr[128 + lane];
}

// ---------------- FP layer 1: (5000x288)x(288->128), relu ----------------
__global__ void __launch_bounds__(128) fp1_kernel(const float* __restrict__ F,
                                                  const float* __restrict__ W,
                                                  const float* __restrict__ b,
                                                  float* __restrict__ H) {
  __shared__ float A[32*FPK];
  int base = blockIdx.x*32, tid = threadIdx.x;
  for (int e = tid; e < 32*FPK; e += 128) {
    int r = e / FPK; int gr = base + r;
    A[e] = (gr < NPCD) ? F[gr*FPK + (e - r*FPK)] : 0.0f;
  }
  __syncthreads();
  const int o = tid;
  float acc[32];
  #pragma unroll
  for (int r = 0; r < 32; r++) acc[r] = b[o];
  for (int kc = 0; kc < 36; kc++) {
    const float4* wp = (const float4*)(W + o*FPK + kc*8);
    float4 w0 = wp[0], w1 = wp[1];
    #pragma unroll
    for (int r = 0; r < 32; r++) {
      const float4* ap = (const float4*)(A + r*FPK + kc*8);
      float4 a0 = ap[0], a1 = ap[1];
      acc[r] += w0.x*a0.x + w0.y*a0.y + w0.z*a0.z + w0.w*a0.w
              + w1.x*a1.x + w1.y*a1.y + w1.z*a1.z + w1.w*a1.w;
    }
  }
  #pragma unroll
  for (int r = 0; r < 32; r++) {
    int gr = base + r;
    if (gr < NPCD) H[gr*HD + o] = fmaxf(acc[r], 0.0f);
  }
}

// ---------------- FP layer 2: (5000x128)x(128->32), relu ----------------
__global__ void __launch_bounds__(256) fp2_kernel(const float* __restrict__ Hin,
                                                  const float* __restrict__ W,
                                                  const float* __restrict__ b,
                                                  float* __restrict__ fpf,
                                                  unsigned* __restrict__ gmax) {
  if (blockIdx.x == 0 && threadIdx.x == 0) *gmax = 0u;  // init for the gmax kernel that follows
  __shared__ float A[32*HD];
  int base = blockIdx.x*32, tid = threadIdx.x;
  for (int e = tid; e < 32*HD; e += 256) {
    int r = e >> 7; int gr = base + r;
    A[e] = (gr < NPCD) ? Hin[gr*HD + (e & 127)] : 0.0f;
  }
  __syncthreads();
  int o = tid & 31, rg = tid >> 5;
  float acc[4];
  #pragma unroll
  for (int j = 0; j < 4; j++) acc[j] = b[o];
  for (int kc = 0; kc < 16; kc++) {
    const float4* wp = (const float4*)(W + o*HD + kc*8);
    float4 w0 = wp[0], w1 = wp[1];
    #pragma unroll
    for (int j = 0; j < 4; j++) {
      int r = rg + (j << 3);
      const float4* ap = (const float4*)(A + r*HD + kc*8);
      float4 a0 = ap[0], a1 = ap[1];
      acc[j] += w0.x*a0.x + w0.y*a0.y + w0.z*a0.z + w0.w*a0.w
              + w1.x*a1.x + w1.y*a1.y + w1.z*a1.z + w1.w*a1.w;
    }
  }
  #pragma unroll
  for (int j = 0; j < 4; j++) {
    int gr = base + rg + (j << 3);
    if (gr < NPCD) fpf[gr*CPCD + o] = fmaxf(acc[j], 0.0f);
  }
}

// ---------------- global max of fp_feat (all >= 0) ----------------
__global__ void gmax_kernel(const float* __restrict__ fpf, unsigned* __restrict__ gmax) {
  int id = blockIdx.x*256 + threadIdx.x;
  float m = (id < NPCD*CPCD) ? fpf[id] : 0.0f;
  #pragma unroll
  for (int off = 1; off < 64; off <<= 1) m = fmaxf(m, __shfl_xor(m, off));
  if ((threadIdx.x & 63) == 0) atomicMax(gmax, __float_as_uint(m));
}

// ---------------- detection scores (wave per point) ----------------
__global__ void det_score_kernel(const float* __restrict__ fpf,
                                 const int* __restrict__ nbd,
                                 const unsigned* __restrict__ gmax,
                                 float* __restrict__ outs) {
  int wv = threadIdx.x >> 6, lane = threadIdx.x & 63;
  int i = blockIdx.x*4 + wv;
  float g = __uint_as_float(*gmax);
  float scale = 1.0f / (g + 1e-6f);
  int c = lane & 31, h = lane >> 5;
  float sum = 0.0f;
  const int* nbr = nbd + i*NBK + h*32;
  for (int k = 0; k < 32; k++) {
    int idx = nbr[k];
    sum += fpf[idx*CPCD + c];
  }
  sum += __shfl_xor(sum, 32);
  float mean = (sum * scale) * 0.015625f;   // /64 exact
  float fi = fpf[i*CPCD + c] * scale;
  float x = fi - mean;
  float lm = fmaxf(x, 0.0f) + log1pf(expf(-fabsf(x)));  // softplus = logaddexp(x,0)
  float dm = fi;
  #pragma unroll
  for (int off = 1; off < 64; off <<= 1) dm = fmaxf(dm, __shfl_xor(dm, off));
  float dw = fi / (1e-6f + dm);
  float pr = lm * dw;
  #pragma unroll
  for (int off = 1; off < 64; off <<= 1) pr = fmaxf(pr, __shfl_xor(pr, off));
  if (lane == 0) outs[i] = pr;
}

// ---------------- outputs: pcd_xyz copy + normalized vote_features ----------------
__global__ void vote_out_kernel(const float* __restrict__ pcd_xyz,
                                const float* __restrict__ fpf,
                                float* __restrict__ dout) {
  int id = blockIdx.x*256 + threadIdx.x;
  if (id < NPCD*3) dout[id] = pcd_xyz[id];
  int r = id - NPCD*3;
  if (r >= 0 && r < NPCD) {
    float ss = 0.0f;
    const float* fr = fpf + r*CPCD;
    #pragma unroll
    for (int cc = 0; cc < CPCD; cc++) ss += fr[cc]*fr[cc];
    float nrm = fmaxf(sqrtf(ss), 1e-12f);
    float* vf = dout + NPCD*3 + NPCD + r*CPCD;
    #pragma unroll
    for (int cc = 0; cc < CPCD; cc++) vf[cc] = fr[cc] / nrm;
  }
}

extern "C" void kernel_launch(void* const* d_in, const int* in_sizes, int n_in,
                              void* d_out, int out_size, void* d_ws, size_t ws_size,
                              hipStream_t stream) {
  const float* pcd_xyz      = (const float*)d_in[0];
  const float* pcd_features = (const float*)d_in[1];
  const float* rgb_xyz      = (const float*)d_in[2];
  const float* rgb_features = (const float*)d_in[3];
  const float* sa_W1 = (const float*)d_in[4];
  const float* sa_b1 = (const float*)d_in[5];
  const float* sa_W2 = (const float*)d_in[6];
  const float* sa_b2 = (const float*)d_in[7];
  const float* sa_W3 = (const float*)d_in[8];
  const float* sa_b3 = (const float*)d_in[9];
  const float* fp_W1 = (const float*)d_in[10];
  const float* fp_b1 = (const float*)d_in[11];
  const float* fp_W2 = (const float*)d_in[12];
  const float* fp_b2 = (const float*)d_in[13];
  float* out = (float*)d_out;

  float* xyz  = (float*)d_ws;            // 60000
  float* feat = xyz  + 60000;            // 3,200,000
  float* W1p  = feat + 3200000;          // 21,504
  float* axyz = W1p  + 21504;            // 12,288
  float* saf  = axyz + 12288;            // 524,288
  float* F    = saf  + 524288;           // 1,440,000
  float* Hb   = F    + 1440000;          // 640,000
  float* fpf  = Hb   + 640000;           // 160,000
  int*   fidx = (int*)(fpf + 160000);    // 4096
  int*   nbsa = fidx + 4096;             // 131,072
  int*   nbdet= nbsa + 131072;           // 320,000
  unsigned* gmaxp = (unsigned*)(nbdet + 320000);

  prep_kernel<<<2048, 256, 0, stream>>>(pcd_xyz, pcd_features, rgb_xyz, rgb_features,
                                        sa_W1, xyz, feat, W1p);
  fps_kernel<<<1, 1024, 0, stream>>>(xyz, fidx, axyz);
  sa_bq_kernel<<<1024, 256, 0, stream>>>(xyz, axyz, nbsa);
  sa_mlp_kernel<<<4096, 128, 0, stream>>>(xyz, feat, axyz, nbsa, W1p, sa_b1,
                                          sa_W2, sa_b2, sa_W3, sa_b3, saf);
  nn_interp_kernel<<<1250, 256, 0, stream>>>(xyz, feat, axyz, saf, F);
  fp1_kernel<<<157, 128, 0, stream>>>(F, fp_W1, fp_b1, Hb);
  fp2_kernel<<<157, 256, 0, stream>>>(Hb, fp_W2, fp_b2, fpf, gmaxp);
  det_bq_kernel<<<1250, 256, 0, stream>>>(pcd_xyz, nbdet);
  gmax_kernel<<<625, 256, 0, stream>>>(fpf, gmaxp);
  det_score_kernel<<<1250, 256, 0, stream>>>(fpf, nbdet, gmaxp, out + NPCD*3);
  vote_out_kernel<<<79, 256, 0, stream>>>(pcd_xyz, fpf, out);
}

// Round 2
// 10311.518 us; speedup vs baseline: 2.0085x; 2.0085x over previous
//
#include <hip/hip_runtime.h>

#define N_ALL 20000
#define NPCD  5000
#define NRGB  15000
#define CPCD  32
#define CRGB  128
#define CF    160
#define NA    4096
#define SANS  32
#define NBK   64
#define K1    163
#define K1P   168
#define HD    128
#define FPK   288

// ---------------- prep: build xyz(20000x3), feat(20000x160), padded sa_W1(128x168) ----------------
__global__ void prep_kernel(const float* __restrict__ pcd_xyz,
                            const float* __restrict__ pcd_feat,
                            const float* __restrict__ rgb_xyz,
                            const float* __restrict__ rgb_feat,
                            const float* __restrict__ sa_W1,
                            float* __restrict__ xyz,
                            float* __restrict__ feat,
                            float* __restrict__ W1p) {
  const int TOT = N_ALL*CF + N_ALL*3 + HD*K1P;
  for (int id = blockIdx.x*blockDim.x + threadIdx.x; id < TOT; id += gridDim.x*blockDim.x) {
    if (id < N_ALL*CF) {
      int r = id / CF, c = id - r*CF;
      float v = 0.0f;
      if (r < NPCD) { if (c < CPCD) v = pcd_feat[r*CPCD + c]; }
      else          { if (c >= CPCD) v = rgb_feat[(c - CPCD)*NRGB + (r - NPCD)]; }
      feat[id] = v;
    } else if (id < N_ALL*CF + N_ALL*3) {
      int e = id - N_ALL*CF;
      xyz[e] = (e < NPCD*3) ? pcd_xyz[e] : rgb_xyz[e - NPCD*3];
    } else {
      int e = id - (N_ALL*CF + N_ALL*3);
      int o = e / K1P, c = e - o*K1P;
      W1p[e] = (c < K1) ? sa_W1[o*K1 + c] : 0.0f;
    }
  }
}

// ---------------- FPS: single block, coords+dists in registers (no spills, 1 barrier/iter) ----------------
// __launch_bounds__(1024, 4): 4 waves/EU min -> 128-VGPR cap; we need ~105 so the
// xs/ys/zs/ds[20] arrays stay in registers (round-1 failure: 64-VGPR cap -> full spill,
// FETCH_SIZE 230+ MB of scratch traffic).
__global__ void __launch_bounds__(1024, 4) fps_kernel(const float* __restrict__ xyz,
                                                      int* __restrict__ fidx,
                                                      float* __restrict__ axyz) {
  #pragma clang fp contract(off)
  const int t = threadIdx.x;
  float xs[20], ys[20], zs[20], ds[20];
  #pragma unroll
  for (int i = 0; i < 20; i++) {
    int p = t + (i << 10);
    if (p < N_ALL) { xs[i]=xyz[3*p]; ys[i]=xyz[3*p+1]; zs[i]=xyz[3*p+2]; ds[i]=1e10f; }
    else           { xs[i]=0.0f; ys[i]=0.0f; zs[i]=0.0f; ds[i]=-1.0f; } // pad never wins (real dists >= 0)
  }
  __shared__ unsigned long long red[2][16];   // double-buffered on iteration parity -> 1 barrier/iter
  float cx = xyz[0], cy = xyz[1], cz = xyz[2];
  if (t == 0) { fidx[0] = 0; axyz[0] = cx; axyz[1] = cy; axyz[2] = cz; }
  const int lane = t & 63, wv = t >> 6;
  for (int it = 1; it < NA; ++it) {
    float bd = -1e30f; int bi = 0;
    #pragma unroll
    for (int i = 0; i < 20; i++) {
      float dx = xs[i]-cx, dy = ys[i]-cy, dz = zs[i]-cz;
      float d  = (dx*dx + dy*dy) + dz*dz;     // plain f32, no contraction (matches numpy)
      float nd = fminf(ds[i], d);
      ds[i] = nd;
      if (nd > bd) { bd = nd; bi = i; }       // ascending i => lowest index on ties
    }
    // pack: high = dist bits (nonneg floats: monotone), low = ~global_index (max => lowest idx)
    unsigned long long pk =
      ((unsigned long long)__float_as_uint(bd) << 32) | (unsigned)(~((bi << 10) + t));
    #pragma unroll
    for (int off = 1; off < 64; off <<= 1) {
      unsigned long long o = __shfl_xor(pk, off);
      pk = (o > pk) ? o : pk;
    }
    const int par = it & 1;
    if (lane == 0) red[par][wv] = pk;
    __syncthreads();
    unsigned long long m = red[par][0];
    #pragma unroll
    for (int w = 1; w < 16; w++) { unsigned long long o = red[par][w]; m = (o > m) ? o : m; }
    unsigned gi = ~(unsigned)(m & 0xFFFFFFFFu);
    // all threads fetch the new center via a broadcast global load (L2-hot);
    // no dynamic register-array indexing, no second barrier.
    cx = xyz[3*gi]; cy = xyz[3*gi + 1]; cz = xyz[3*gi + 2];
    if (t == 0) {
      fidx[it] = (int)gi;
      axyz[3*it] = cx; axyz[3*it+1] = cy; axyz[3*it+2] = cz;
    }
  }
}

// ---------------- ball query (wave per center): first K smallest indices with d2 < r2 ----------------
__global__ void sa_bq_kernel(const float* __restrict__ xyz,
                             const float* __restrict__ axyz,
                             int* __restrict__ nb) {
  #pragma clang fp contract(off)
  int wv = threadIdx.x >> 6, lane = threadIdx.x & 63;
  int a = blockIdx.x*4 + wv;
  float ax = axyz[3*a], ay = axyz[3*a+1], az = axyz[3*a+2];
  int cnt = 0, my = 0;
  for (int base = 0; base < N_ALL; base += 64) {
    int p = base + lane;
    bool in = false;
    if (p < N_ALL) {
      float dx = ax - xyz[3*p], dy = ay - xyz[3*p+1], dz = az - xyz[3*p+2];
      float d2 = (dx*dx + dy*dy) + dz*dz;
      in = d2 < 0.01f;
    }
    unsigned long long mask = __ballot(in);
    while (mask && cnt < SANS) {
      int b = __builtin_ctzll(mask);
      mask &= mask - 1;
      if (cnt == lane) my = base + b;
      cnt++;
    }
    if (cnt >= SANS) break;
  }
  int f0 = __shfl(my, 0);
  if (lane < SANS) nb[a*SANS + lane] = (lane < cnt) ? my : f0;
}

__global__ void det_bq_kernel(const float* __restrict__ pxyz,
                              int* __restrict__ nb) {
  #pragma clang fp contract(off)
  int wv = threadIdx.x >> 6, lane = threadIdx.x & 63;
  int i = blockIdx.x*4 + wv;
  float ax = pxyz[3*i], ay = pxyz[3*i+1], az = pxyz[3*i+2];
  int cnt = 0, my = 0;
  for (int base = 0; base < NPCD; base += 64) {
    int p = base + lane;
    bool in = false;
    if (p < NPCD) {
      float dx = ax - pxyz[3*p], dy = ay - pxyz[3*p+1], dz = az - pxyz[3*p+2];
      float d2 = (dx*dx + dy*dy) + dz*dz;
      in = d2 < 0.04f;
    }
    unsigned long long mask = __ballot(in);
    while (mask && cnt < NBK) {
      int b = __builtin_ctzll(mask);
      mask &= mask - 1;
      if (cnt == lane) my = base + b;
      cnt++;
    }
    if (cnt >= NBK) break;
  }
  int f0 = __shfl(my, 0);
  nb[i*NBK + lane] = (lane < cnt) ? my : f0;
}

// ---------------- SA: gather g(32x163) -> 3x MLP(128) -> maxpool, one anchor per block ----------------
__global__ void __launch_bounds__(128) sa_mlp_kernel(const float* __restrict__ xyz,
                                                     const float* __restrict__ feat,
                                                     const float* __restrict__ axyz,
                                                     const int* __restrict__ nb,
                                                     const float* __restrict__ W1p,
                                                     const float* __restrict__ b1,
                                                     const float* __restrict__ W2,
                                                     const float* __restrict__ b2,
                                                     const float* __restrict__ W3,
                                                     const float* __restrict__ b3,
                                                     float* __restrict__ sa_feat) {
  __shared__ float g[SANS*K1P];     // 21504 B, reused as h2
  __shared__ float h1[SANS*HD];     // 16384 B
  __shared__ int nbs[SANS];
  int a = blockIdx.x, tid = threadIdx.x;
  if (tid < SANS) nbs[tid] = nb[a*SANS + tid];
  float ax = axyz[3*a], ay = axyz[3*a+1], az = axyz[3*a+2];
  __syncthreads();
  for (int e = tid; e < SANS*K1P; e += 128) {
    int s = e / K1P, c = e - s*K1P;
    float v = 0.0f;
    int p = nbs[s];
    if (c < 3) {
      float pc  = xyz[3*p + c];
      float acx = (c == 0) ? ax : ((c == 1) ? ay : az);
      v = (pc - acx) / 0.1f;
    } else if (c < K1) {
      v = feat[p*CF + (c - 3)];
    }
    g[e] = v;
  }
  __syncthreads();
  const int o = tid;
  float acc[SANS];
  // layer 1: K = 168 (zero padded)
  #pragma unroll
  for (int s = 0; s < SANS; s++) acc[s] = b1[o];
  for (int kc = 0; kc < 21; kc++) {
    const float4* wp = (const float4*)(W1p + o*K1P + kc*8);
    float4 w0 = wp[0], w1 = wp[1];
    #pragma unroll
    for (int s = 0; s < SANS; s++) {
      const float4* gp = (const float4*)(g + s*K1P + kc*8);
      float4 g0 = gp[0], g1 = gp[1];
      acc[s] += w0.x*g0.x + w0.y*g0.y + w0.z*g0.z + w0.w*g0.w
              + w1.x*g1.x + w1.y*g1.y + w1.z*g1.z + w1.w*g1.w;
    }
  }
  #pragma unroll
  for (int s = 0; s < SANS; s++) h1[s*HD + o] = fmaxf(acc[s], 0.0f);
  __syncthreads();
  // layer 2: K = 128, write h2 into g buffer
  #pragma unroll
  for (int s = 0; s < SANS; s++) acc[s] = b2[o];
  for (int kc = 0; kc < 16; kc++) {
    const float4* wp = (const float4*)(W2 + o*HD + kc*8);
    float4 w0 = wp[0], w1 = wp[1];
    #pragma unroll
    for (int s = 0; s < SANS; s++) {
      const float4* gp = (const float4*)(h1 + s*HD + kc*8);
      float4 g0 = gp[0], g1 = gp[1];
      acc[s] += w0.x*g0.x + w0.y*g0.y + w0.z*g0.z + w0.w*g0.w
              + w1.x*g1.x + w1.y*g1.y + w1.z*g1.z + w1.w*g1.w;
    }
  }
  float* h2 = g;
  #pragma unroll
  for (int s = 0; s < SANS; s++) h2[s*HD + o] = fmaxf(acc[s], 0.0f);
  __syncthreads();
  // layer 3 + max pool
  #pragma unroll
  for (int s = 0; s < SANS; s++) acc[s] = b3[o];
  for (int kc = 0; kc < 16; kc++) {
    const float4* wp = (const float4*)(W3 + o*HD + kc*8);
    float4 w0 = wp[0], w1 = wp[1];
    #pragma unroll
    for (int s = 0; s < SANS; s++) {
      const float4* gp = (const float4*)(h2 + s*HD + kc*8);
      float4 g0 = gp[0], g1 = gp[1];
      acc[s] += w0.x*g0.x + w0.y*g0.y + w0.z*g0.z + w0.w*g0.w
              + w1.x*g1.x + w1.y*g1.y + w1.z*g1.z + w1.w*g1.w;
    }
  }
  float m = 0.0f;
  #pragma unroll
  for (int s = 0; s < SANS; s++) m = fmaxf(m, fmaxf(acc[s], 0.0f));
  sa_feat[a*HD + o] = m;
}

// ---------------- 3-NN interp (first 5000 points only) + build F row [interp(128)|feat(160)] ----------------
#define INSERT3(v) { if ((v) < t0){ t2=t1; t1=t0; t0=(v);} \
                     else if ((v) < t1){ t2=t1; t1=(v);} \
                     else if ((v) < t2){ t2=(v);} }

__global__ void nn_interp_kernel(const float* __restrict__ xyz,
                                 const float* __restrict__ feat,
                                 const float* __restrict__ axyz,
                                 const float* __restrict__ sa_feat,
                                 float* __restrict__ F) {
  #pragma clang fp contract(off)
  int wv = threadIdx.x >> 6, lane = threadIdx.x & 63;
  int p = blockIdx.x*4 + wv;
  float px = xyz[3*p], py = xyz[3*p+1], pz = xyz[3*p+2];
  unsigned long long t0 = ~0ull, t1 = ~0ull, t2 = ~0ull;
  for (int j = 0; j < 64; j++) {
    int a = lane + (j << 6);
    float dx = px - axyz[3*a], dy = py - axyz[3*a+1], dz = pz - axyz[3*a+2];
    float d2 = (dx*dx + dy*dy) + dz*dz;
    unsigned long long pk = ((unsigned long long)__float_as_uint(d2) << 32) | (unsigned)a;
    INSERT3(pk);
  }
  #pragma unroll
  for (int off = 1; off < 64; off <<= 1) {
    unsigned long long b0 = __shfl_xor(t0, off);
    unsigned long long b1 = __shfl_xor(t1, off);
    unsigned long long b2 = __shfl_xor(t2, off);
    INSERT3(b0); INSERT3(b1); INSERT3(b2);
  }
  float d0 = __uint_as_float((unsigned)(t0 >> 32));
  float d1 = __uint_as_float((unsigned)(t1 >> 32));
  float d2v = __uint_as_float((unsigned)(t2 >> 32));
  int a0 = (int)(t0 & 0xFFFFFFFFull), a1 = (int)(t1 & 0xFFFFFFFFull), a2 = (int)(t2 & 0xFFFFFFFFull);
  float w0 = 1.0f/(d0 + 1e-8f), w1 = 1.0f/(d1 + 1e-8f), w2 = 1.0f/(d2v + 1e-8f);
  float wsum = w0 + w1 + w2;
  w0 /= wsum; w1 /= wsum; w2 /= wsum;
  const float* s0 = sa_feat + a0*HD;
  const float* s1 = sa_feat + a1*HD;
  const float* s2 = sa_feat + a2*HD;
  float* Fr = F + p*FPK;
  Fr[lane]      = w0*s0[lane]    + w1*s1[lane]    + w2*s2[lane];
  Fr[lane + 64] = w0*s0[lane+64] + w1*s1[lane+64] + w2*s2[lane+64];
  const float* fr = feat + p*CF;
  Fr[HD + lane]      = fr[lane];
  Fr[HD + lane + 64] = fr[lane + 64];
  if (lane < 32) Fr[HD + 128 + lane] = fr[128 + lane];
}

// ---------------- FP layer 1: (5000x288)x(288->128), relu ----------------
__global__ void __launch_bounds__(128) fp1_kernel(const float* __restrict__ F,
                                                  const float* __restrict__ W,
                                                  const float* __restrict__ b,
                                                  float* __restrict__ H) {
  __shared__ float A[32*FPK];
  int base = blockIdx.x*32, tid = threadIdx.x;
  for (int e = tid; e < 32*FPK; e += 128) {
    int r = e / FPK; int gr = base + r;
    A[e] = (gr < NPCD) ? F[gr*FPK + (e - r*FPK)] : 0.0f;
  }
  __syncthreads();
  const int o = tid;
  float acc[32];
  #pragma unroll
  for (int r = 0; r < 32; r++) acc[r] = b[o];
  for (int kc = 0; kc < 36; kc++) {
    const float4* wp = (const float4*)(W + o*FPK + kc*8);
    float4 w0 = wp[0], w1 = wp[1];
    #pragma unroll
    for (int r = 0; r < 32; r++) {
      const float4* ap = (const float4*)(A + r*FPK + kc*8);
      float4 a0 = ap[0], a1 = ap[1];
      acc[r] += w0.x*a0.x + w0.y*a0.y + w0.z*a0.z + w0.w*a0.w
              + w1.x*a1.x + w1.y*a1.y + w1.z*a1.z + w1.w*a1.w;
    }
  }
  #pragma unroll
  for (int r = 0; r < 32; r++) {
    int gr = base + r;
    if (gr < NPCD) H[gr*HD + o] = fmaxf(acc[r], 0.0f);
  }
}

// ---------------- FP layer 2: (5000x128)x(128->32), relu ----------------
__global__ void __launch_bounds__(256) fp2_kernel(const float* __restrict__ Hin,
                                                  const float* __restrict__ W,
                                                  const float* __restrict__ b,
                                                  float* __restrict__ fpf,
                                                  unsigned* __restrict__ gmax) {
  if (blockIdx.x == 0 && threadIdx.x == 0) *gmax = 0u;  // init for the gmax kernel that follows
  __shared__ float A[32*HD];
  int base = blockIdx.x*32, tid = threadIdx.x;
  for (int e = tid; e < 32*HD; e += 256) {
    int r = e >> 7; int gr = base + r;
    A[e] = (gr < NPCD) ? Hin[gr*HD + (e & 127)] : 0.0f;
  }
  __syncthreads();
  int o = tid & 31, rg = tid >> 5;
  float acc[4];
  #pragma unroll
  for (int j = 0; j < 4; j++) acc[j] = b[o];
  for (int kc = 0; kc < 16; kc++) {
    const float4* wp = (const float4*)(W + o*HD + kc*8);
    float4 w0 = wp[0], w1 = wp[1];
    #pragma unroll
    for (int j = 0; j < 4; j++) {
      int r = rg + (j << 3);
      const float4* ap = (const float4*)(A + r*HD + kc*8);
      float4 a0 = ap[0], a1 = ap[1];
      acc[j] += w0.x*a0.x + w0.y*a0.y + w0.z*a0.z + w0.w*a0.w
              + w1.x*a1.x + w1.y*a1.y + w1.z*a1.z + w1.w*a1.w;
    }
  }
  #pragma unroll
  for (int j = 0; j < 4; j++) {
    int gr = base + rg + (j << 3);
    if (gr < NPCD) fpf[gr*CPCD + o] = fmaxf(acc[j], 0.0f);
  }
}

// ---------------- global max of fp_feat (all >= 0) ----------------
__global__ void gmax_kernel(const float* __restrict__ fpf, unsigned* __restrict__ gmax) {
  int id = blockIdx.x*256 + threadIdx.x;
  float m = (id < NPCD*CPCD) ? fpf[id] : 0.0f;
  #pragma unroll
  for (int off = 1; off < 64; off <<= 1) m = fmaxf(m, __shfl_xor(m, off));
  if ((threadIdx.x & 63) == 0) atomicMax(gmax, __float_as_uint(m));
}

// ---------------- detection scores (wave per point) ----------------
__global__ void det_score_kernel(const float* __restrict__ fpf,
                                 const int* __restrict__ nbd,
                                 const unsigned* __restrict__ gmax,
                                 float* __restrict__ outs) {
  int wv = threadIdx.x >> 6, lane = threadIdx.x & 63;
  int i = blockIdx.x*4 + wv;
  float g = __uint_as_float(*gmax);
  float scale = 1.0f / (g + 1e-6f);
  int c = lane & 31, h = lane >> 5;
  float sum = 0.0f;
  const int* nbr = nbd + i*NBK + h*32;
  for (int k = 0; k < 32; k++) {
    int idx = nbr[k];
    sum += fpf[idx*CPCD + c];
  }
  sum += __shfl_xor(sum, 32);
  float mean = (sum * scale) * 0.015625f;   // /64 exact
  float fi = fpf[i*CPCD + c] * scale;
  float x = fi - mean;
  float lm = fmaxf(x, 0.0f) + log1pf(expf(-fabsf(x)));  // softplus = logaddexp(x,0)
  float dm = fi;
  #pragma unroll
  for (int off = 1; off < 64; off <<= 1) dm = fmaxf(dm, __shfl_xor(dm, off));
  float dw = fi / (1e-6f + dm);
  float pr = lm * dw;
  #pragma unroll
  for (int off = 1; off < 64; off <<= 1) pr = fmaxf(pr, __shfl_xor(pr, off));
  if (lane == 0) outs[i] = pr;
}

// ---------------- outputs: pcd_xyz copy + normalized vote_features ----------------
__global__ void vote_out_kernel(const float* __restrict__ pcd_xyz,
                                const float* __restrict__ fpf,
                                float* __restrict__ dout) {
  int id = blockIdx.x*256 + threadIdx.x;
  if (id < NPCD*3) dout[id] = pcd_xyz[id];
  int r = id - NPCD*3;
  if (r >= 0 && r < NPCD) {
    float ss = 0.0f;
    const float* fr = fpf + r*CPCD;
    #pragma unroll
    for (int cc = 0; cc < CPCD; cc++) ss += fr[cc]*fr[cc];
    float nrm = fmaxf(sqrtf(ss), 1e-12f);
    float* vf = dout + NPCD*3 + NPCD + r*CPCD;
    #pragma unroll
    for (int cc = 0; cc < CPCD; cc++) vf[cc] = fr[cc] / nrm;
  }
}

extern "C" void kernel_launch(void* const* d_in, const int* in_sizes, int n_in,
                              void* d_out, int out_size, void* d_ws, size_t ws_size,
                              hipStream_t stream) {
  const float* pcd_xyz      = (const float*)d_in[0];
  const float* pcd_features = (const float*)d_in[1];
  const float* rgb_xyz      = (const float*)d_in[2];
  const float* rgb_features = (const float*)d_in[3];
  const float* sa_W1 = (const float*)d_in[4];
  const float* sa_b1 = (const float*)d_in[5];
  const float* sa_W2 = (const float*)d_in[6];
  const float* sa_b2 = (const float*)d_in[7];
  const float* sa_W3 = (const float*)d_in[8];
  const float* sa_b3 = (const float*)d_in[9];
  const float* fp_W1 = (const float*)d_in[10];
  const float* fp_b1 = (const float*)d_in[11];
  const float* fp_W2 = (const float*)d_in[12];
  const float* fp_b2 = (const float*)d_in[13];
  float* out = (float*)d_out;

  float* xyz  = (float*)d_ws;            // 60000
  float* feat = xyz  + 60000;            // 3,200,000
  float* W1p  = feat + 3200000;          // 21,504
  float* axyz = W1p  + 21504;            // 12,288
  float* saf  = axyz + 12288;            // 524,288
  float* F    = saf  + 524288;           // 1,440,000
  float* Hb   = F    + 1440000;          // 640,000
  float* fpf  = Hb   + 640000;           // 160,000
  int*   fidx = (int*)(fpf + 160000);    // 4096
  int*   nbsa = fidx + 4096;             // 131,072
  int*   nbdet= nbsa + 131072;           // 320,000
  unsigned* gmaxp = (unsigned*)(nbdet + 320000);

  prep_kernel<<<2048, 256, 0, stream>>>(pcd_xyz, pcd_features, rgb_xyz, rgb_features,
                                        sa_W1, xyz, feat, W1p);
  fps_kernel<<<1, 1024, 0, stream>>>(xyz, fidx, axyz);
  sa_bq_kernel<<<1024, 256, 0, stream>>>(xyz, axyz, nbsa);
  sa_mlp_kernel<<<4096, 128, 0, stream>>>(xyz, feat, axyz, nbsa, W1p, sa_b1,
                                          sa_W2, sa_b2, sa_W3, sa_b3, saf);
  nn_interp_kernel<<<1250, 256, 0, stream>>>(xyz, feat, axyz, saf, F);
  fp1_kernel<<<157, 128, 0, stream>>>(F, fp_W1, fp_b1, Hb);
  fp2_kernel<<<157, 256, 0, stream>>>(Hb, fp_W2, fp_b2, fpf, gmaxp);
  det_bq_kernel<<<1250, 256, 0, stream>>>(pcd_xyz, nbdet);
  gmax_kernel<<<625, 256, 0, stream>>>(fpf, gmaxp);
  det_score_kernel<<<1250, 256, 0, stream>>>(fpf, nbdet, gmaxp, out + NPCD*3);
  vote_out_kernel<<<79, 256, 0, stream>>>(pcd_xyz, fpf, out);
}

// Round 3
// 8613.992 us; speedup vs baseline: 2.4043x; 1.1971x over previous
//
#include <hip/hip_runtime.h>

#define N_ALL 20000
#define NPCD  5000
#define NRGB  15000
#define CPCD  32
#define CRGB  128
#define CF    160
#define NA    4096
#define SANS  32
#define NBK   64
#define K1    163
#define K1P   168
#define HD    128
#define FPK   288
#define NSOA  20480   // 2048*10 — pair-SoA padded length for FPS

// ---------------- prep: build xyz(20000x3), SoA copies, feat(20000x160), padded sa_W1(128x168) ----------------
__global__ void prep_kernel(const float* __restrict__ pcd_xyz,
                            const float* __restrict__ pcd_feat,
                            const float* __restrict__ rgb_xyz,
                            const float* __restrict__ rgb_feat,
                            const float* __restrict__ sa_W1,
                            float* __restrict__ xyz,
                            float* __restrict__ feat,
                            float* __restrict__ W1p,
                            float* __restrict__ xsoa,
                            float* __restrict__ ysoa,
                            float* __restrict__ zsoa) {
  const int TOT = N_ALL*CF + N_ALL*3 + HD*K1P + NSOA;
  for (int id = blockIdx.x*blockDim.x + threadIdx.x; id < TOT; id += gridDim.x*blockDim.x) {
    if (id < N_ALL*CF) {
      int r = id / CF, c = id - r*CF;
      float v = 0.0f;
      if (r < NPCD) { if (c < CPCD) v = pcd_feat[r*CPCD + c]; }
      else          { if (c >= CPCD) v = rgb_feat[(c - CPCD)*NRGB + (r - NPCD)]; }
      feat[id] = v;
    } else if (id < N_ALL*CF + N_ALL*3) {
      int e = id - N_ALL*CF;
      xyz[e] = (e < NPCD*3) ? pcd_xyz[e] : rgb_xyz[e - NPCD*3];
    } else if (id < N_ALL*CF + N_ALL*3 + HD*K1P) {
      int e = id - (N_ALL*CF + N_ALL*3);
      int o = e / K1P, c = e - o*K1P;
      W1p[e] = (c < K1) ? sa_W1[o*K1 + c] : 0.0f;
    } else {
      int p = id - (N_ALL*CF + N_ALL*3 + HD*K1P);  // 0..NSOA-1
      float vx = 0.0f, vy = 0.0f, vz = 0.0f;
      if (p < NPCD)      { vx = pcd_xyz[3*p]; vy = pcd_xyz[3*p+1]; vz = pcd_xyz[3*p+2]; }
      else if (p < N_ALL){ int q = p - NPCD; vx = rgb_xyz[3*q]; vy = rgb_xyz[3*q+1]; vz = rgb_xyz[3*q+2]; }
      xsoa[p] = vx; ysoa[p] = vy; zsoa[p] = vz;
    }
  }
}

// ---------------- FPS: single block, pair-SoA coords resident in registers ----------------
// Single-block kernel => HW occupancy is fixed at 16 waves (4/EU) regardless of VGPR count,
// so demanding a high-occupancy register budget is pure loss. amdgpu_waves_per_eu(2,4)
// caps the budget at 256 (target 4/EU): the 80-float coord+dist working set stays in
// registers. Round-2 failure mode: 64-VGPR budget -> compiler rematerialized the coord
// loads from global every iteration (122 MB FETCH, VALU-bound on addressing).
__global__ void __launch_bounds__(1024)
__attribute__((amdgpu_waves_per_eu(2, 4)))
fps_kernel(const float* __restrict__ xsoa,
           const float* __restrict__ ysoa,
           const float* __restrict__ zsoa,
           int* __restrict__ fidx,
           float* __restrict__ axyz) {
  #pragma clang fp contract(off)
  const int t = threadIdx.x;
  const int lane = t & 63, wv = t >> 6;
  // thread t owns point pairs p = 2048*j + 2t + e, j in [0,10), e in {0,1}
  float xs[20], ys[20], zs[20], ds[20];
  #pragma unroll
  for (int j = 0; j < 10; j++) {
    int p = (j << 11) + (t << 1);
    float2 vx = *(const float2*)(xsoa + p);
    float2 vy = *(const float2*)(ysoa + p);
    float2 vz = *(const float2*)(zsoa + p);
    xs[2*j] = vx.x; xs[2*j+1] = vx.y;
    ys[2*j] = vy.x; ys[2*j+1] = vy.y;
    zs[2*j] = vz.x; zs[2*j+1] = vz.y;
    ds[2*j]   = (p     < N_ALL) ? 1e10f : -1.0f;   // pads never win (real dists >= 0)
    ds[2*j+1] = (p + 1 < N_ALL) ? 1e10f : -1.0f;
  }
  __shared__ float    wmax[2][16];
  __shared__ unsigned slot[2];
  if (t == 0) { slot[0] = 0xFFFFFFFFu; slot[1] = 0xFFFFFFFFu; }
  float cx = xsoa[0], cy = ysoa[0], cz = zsoa[0];
  if (t == 0) { fidx[0] = 0; axyz[0] = cx; axyz[1] = cy; axyz[2] = cz; }
  for (int it = 1; it < NA; ++it) {
    const int par = it & 1;
    // min-dist update only (argmax deferred): packable pair math, identical rounding to numpy
    #pragma unroll
    for (int j = 0; j < 10; j++) {
      float dx0 = xs[2*j]   - cx, dy0 = ys[2*j]   - cy, dz0 = zs[2*j]   - cz;
      float dx1 = xs[2*j+1] - cx, dy1 = ys[2*j+1] - cy, dz1 = zs[2*j+1] - cz;
      float d0 = (dx0*dx0 + dy0*dy0) + dz0*dz0;
      float d1 = (dx1*dx1 + dy1*dy1) + dz1*dz1;
      ds[2*j]   = fminf(ds[2*j],   d0);
      ds[2*j+1] = fminf(ds[2*j+1], d1);
    }
    // local fold
    float tmax = ds[0];
    #pragma unroll
    for (int i = 1; i < 20; i++) tmax = fmaxf(tmax, ds[i]);
    // wave reduce (value only)
    float wm = tmax;
    #pragma unroll
    for (int off = 1; off < 64; off <<= 1) wm = fmaxf(wm, __shfl_xor(wm, off));
    if (lane == 0) wmax[par][wv] = wm;
    __syncthreads();
    float M = wmax[par][0];
    #pragma unroll
    for (int w = 1; w < 16; w++) M = fmaxf(M, wmax[par][w]);
    if (t == 0) slot[par ^ 1] = 0xFFFFFFFFu;   // reset other slot for next iter (safe: not read until then)
    // rare branch: only threads holding the max scan for their lowest matching global index
    if (tmax == M) {
      unsigned best = 0xFFFFFFFFu;
      #pragma unroll
      for (int i = 19; i >= 0; i--)
        if (ds[i] == M) best = ((unsigned)(i >> 1) << 11) + ((unsigned)t << 1) + (unsigned)(i & 1);
      atomicMin(&slot[par], best);   // exact lowest-index tie-break
    }
    __syncthreads();
    unsigned gi = slot[par];
    cx = xsoa[gi]; cy = ysoa[gi]; cz = zsoa[gi];
    if (t == 0) {
      fidx[it] = (int)gi;
      axyz[3*it] = cx; axyz[3*it+1] = cy; axyz[3*it+2] = cz;
    }
  }
}

// ---------------- ball query (wave per center): first K smallest indices with d2 < r2 ----------------
__global__ void sa_bq_kernel(const float* __restrict__ xyz,
                             const float* __restrict__ axyz,
                             int* __restrict__ nb) {
  #pragma clang fp contract(off)
  int wv = threadIdx.x >> 6, lane = threadIdx.x & 63;
  int a = blockIdx.x*4 + wv;
  float ax = axyz[3*a], ay = axyz[3*a+1], az = axyz[3*a+2];
  int cnt = 0, my = 0;
  for (int base = 0; base < N_ALL; base += 64) {
    int p = base + lane;
    bool in = false;
    if (p < N_ALL) {
      float dx = ax - xyz[3*p], dy = ay - xyz[3*p+1], dz = az - xyz[3*p+2];
      float d2 = (dx*dx + dy*dy) + dz*dz;
      in = d2 < 0.01f;
    }
    unsigned long long mask = __ballot(in);
    while (mask && cnt < SANS) {
      int b = __builtin_ctzll(mask);
      mask &= mask - 1;
      if (cnt == lane) my = base + b;
      cnt++;
    }
    if (cnt >= SANS) break;
  }
  int f0 = __shfl(my, 0);
  if (lane < SANS) nb[a*SANS + lane] = (lane < cnt) ? my : f0;
}

__global__ void det_bq_kernel(const float* __restrict__ pxyz,
                              int* __restrict__ nb) {
  #pragma clang fp contract(off)
  int wv = threadIdx.x >> 6, lane = threadIdx.x & 63;
  int i = blockIdx.x*4 + wv;
  float ax = pxyz[3*i], ay = pxyz[3*i+1], az = pxyz[3*i+2];
  int cnt = 0, my = 0;
  for (int base = 0; base < NPCD; base += 64) {
    int p = base + lane;
    bool in = false;
    if (p < NPCD) {
      float dx = ax - pxyz[3*p], dy = ay - pxyz[3*p+1], dz = az - pxyz[3*p+2];
      float d2 = (dx*dx + dy*dy) + dz*dz;
      in = d2 < 0.04f;
    }
    unsigned long long mask = __ballot(in);
    while (mask && cnt < NBK) {
      int b = __builtin_ctzll(mask);
      mask &= mask - 1;
      if (cnt == lane) my = base + b;
      cnt++;
    }
    if (cnt >= NBK) break;
  }
  int f0 = __shfl(my, 0);
  nb[i*NBK + lane] = (lane < cnt) ? my : f0;
}

// ---------------- SA: gather g(32x163) -> 3x MLP(128) -> maxpool, one anchor per block ----------------
__global__ void __launch_bounds__(128) sa_mlp_kernel(const float* __restrict__ xyz,
                                                     const float* __restrict__ feat,
                                                     const float* __restrict__ axyz,
                                                     const int* __restrict__ nb,
                                                     const float* __restrict__ W1p,
                                                     const float* __restrict__ b1,
                                                     const float* __restrict__ W2,
                                                     const float* __restrict__ b2,
                                                     const float* __restrict__ W3,
                                                     const float* __restrict__ b3,
                                                     float* __restrict__ sa_feat) {
  __shared__ float g[SANS*K1P];     // 21504 B, reused as h2
  __shared__ float h1[SANS*HD];     // 16384 B
  __shared__ int nbs[SANS];
  int a = blockIdx.x, tid = threadIdx.x;
  if (tid < SANS) nbs[tid] = nb[a*SANS + tid];
  float ax = axyz[3*a], ay = axyz[3*a+1], az = axyz[3*a+2];
  __syncthreads();
  for (int e = tid; e < SANS*K1P; e += 128) {
    int s = e / K1P, c = e - s*K1P;
    float v = 0.0f;
    int p = nbs[s];
    if (c < 3) {
      float pc  = xyz[3*p + c];
      float acx = (c == 0) ? ax : ((c == 1) ? ay : az);
      v = (pc - acx) / 0.1f;
    } else if (c < K1) {
      v = feat[p*CF + (c - 3)];
    }
    g[e] = v;
  }
  __syncthreads();
  const int o = tid;
  float acc[SANS];
  // layer 1: K = 168 (zero padded)
  #pragma unroll
  for (int s = 0; s < SANS; s++) acc[s] = b1[o];
  for (int kc = 0; kc < 21; kc++) {
    const float4* wp = (const float4*)(W1p + o*K1P + kc*8);
    float4 w0 = wp[0], w1 = wp[1];
    #pragma unroll
    for (int s = 0; s < SANS; s++) {
      const float4* gp = (const float4*)(g + s*K1P + kc*8);
      float4 g0 = gp[0], g1 = gp[1];
      acc[s] += w0.x*g0.x + w0.y*g0.y + w0.z*g0.z + w0.w*g0.w
              + w1.x*g1.x + w1.y*g1.y + w1.z*g1.z + w1.w*g1.w;
    }
  }
  #pragma unroll
  for (int s = 0; s < SANS; s++) h1[s*HD + o] = fmaxf(acc[s], 0.0f);
  __syncthreads();
  // layer 2: K = 128, write h2 into g buffer
  #pragma unroll
  for (int s = 0; s < SANS; s++) acc[s] = b2[o];
  for (int kc = 0; kc < 16; kc++) {
    const float4* wp = (const float4*)(W2 + o*HD + kc*8);
    float4 w0 = wp[0], w1 = wp[1];
    #pragma unroll
    for (int s = 0; s < SANS; s++) {
      const float4* gp = (const float4*)(h1 + s*HD + kc*8);
      float4 g0 = gp[0], g1 = gp[1];
      acc[s] += w0.x*g0.x + w0.y*g0.y + w0.z*g0.z + w0.w*g0.w
              + w1.x*g1.x + w1.y*g1.y + w1.z*g1.z + w1.w*g1.w;
    }
  }
  float* h2 = g;
  #pragma unroll
  for (int s = 0; s < SANS; s++) h2[s*HD + o] = fmaxf(acc[s], 0.0f);
  __syncthreads();
  // layer 3 + max pool
  #pragma unroll
  for (int s = 0; s < SANS; s++) acc[s] = b3[o];
  for (int kc = 0; kc < 16; kc++) {
    const float4* wp = (const float4*)(W3 + o*HD + kc*8);
    float4 w0 = wp[0], w1 = wp[1];
    #pragma unroll
    for (int s = 0; s < SANS; s++) {
      const float4* gp = (const float4*)(h2 + s*HD + kc*8);
      float4 g0 = gp[0], g1 = gp[1];
      acc[s] += w0.x*g0.x + w0.y*g0.y + w0.z*g0.z + w0.w*g0.w
              + w1.x*g1.x + w1.y*g1.y + w1.z*g1.z + w1.w*g1.w;
    }
  }
  float m = 0.0f;
  #pragma unroll
  for (int s = 0; s < SANS; s++) m = fmaxf(m, fmaxf(acc[s], 0.0f));
  sa_feat[a*HD + o] = m;
}

// ---------------- 3-NN interp (first 5000 points only) + build F row [interp(128)|feat(160)] ----------------
#define INSERT3(v) { if ((v) < t0){ t2=t1; t1=t0; t0=(v);} \
                     else if ((v) < t1){ t2=t1; t1=(v);} \
                     else if ((v) < t2){ t2=(v);} }

__global__ void nn_interp_kernel(const float* __restrict__ xyz,
                                 const float* __restrict__ feat,
                                 const float* __restrict__ axyz,
                                 const float* __restrict__ sa_feat,
                                 float* __restrict__ F) {
  #pragma clang fp contract(off)
  int wv = threadIdx.x >> 6, lane = threadIdx.x & 63;
  int p = blockIdx.x*4 + wv;
  float px = xyz[3*p], py = xyz[3*p+1], pz = xyz[3*p+2];
  unsigned long long t0 = ~0ull, t1 = ~0ull, t2 = ~0ull;
  for (int j = 0; j < 64; j++) {
    int a = lane + (j << 6);
    float dx = px - axyz[3*a], dy = py - axyz[3*a+1], dz = pz - axyz[3*a+2];
    float d2 = (dx*dx + dy*dy) + dz*dz;
    unsigned long long pk = ((unsigned long long)__float_as_uint(d2) << 32) | (unsigned)a;
    INSERT3(pk);
  }
  #pragma unroll
  for (int off = 1; off < 64; off <<= 1) {
    unsigned long long b0 = __shfl_xor(t0, off);
    unsigned long long b1 = __shfl_xor(t1, off);
    unsigned long long b2 = __shfl_xor(t2, off);
    INSERT3(b0); INSERT3(b1); INSERT3(b2);
  }
  float d0 = __uint_as_float((unsigned)(t0 >> 32));
  float d1 = __uint_as_float((unsigned)(t1 >> 32));
  float d2v = __uint_as_float((unsigned)(t2 >> 32));
  int a0 = (int)(t0 & 0xFFFFFFFFull), a1 = (int)(t1 & 0xFFFFFFFFull), a2 = (int)(t2 & 0xFFFFFFFFull);
  float w0 = 1.0f/(d0 + 1e-8f), w1 = 1.0f/(d1 + 1e-8f), w2 = 1.0f/(d2v + 1e-8f);
  float wsum = w0 + w1 + w2;
  w0 /= wsum; w1 /= wsum; w2 /= wsum;
  const float* s0 = sa_feat + a0*HD;
  const float* s1 = sa_feat + a1*HD;
  const float* s2 = sa_feat + a2*HD;
  float* Fr = F + p*FPK;
  Fr[lane]      = w0*s0[lane]    + w1*s1[lane]    + w2*s2[lane];
  Fr[lane + 64] = w0*s0[lane+64] + w1*s1[lane+64] + w2*s2[lane+64];
  const float* fr = feat + p*CF;
  Fr[HD + lane]      = fr[lane];
  Fr[HD + lane + 64] = fr[lane + 64];
  if (lane < 32) Fr[HD + 128 + lane] = fr[128 + lane];
}

// ---------------- FP layer 1: (5000x288)x(288->128), relu ----------------
__global__ void __launch_bounds__(128) fp1_kernel(const float* __restrict__ F,
                                                  const float* __restrict__ W,
                                                  const float* __restrict__ b,
                                                  float* __restrict__ H) {
  __shared__ float A[32*FPK];
  int base = blockIdx.x*32, tid = threadIdx.x;
  for (int e = tid; e < 32*FPK; e += 128) {
    int r = e / FPK; int gr = base + r;
    A[e] = (gr < NPCD) ? F[gr*FPK + (e - r*FPK)] : 0.0f;
  }
  __syncthreads();
  const int o = tid;
  float acc[32];
  #pragma unroll
  for (int r = 0; r < 32; r++) acc[r] = b[o];
  for (int kc = 0; kc < 36; kc++) {
    const float4* wp = (const float4*)(W + o*FPK + kc*8);
    float4 w0 = wp[0], w1 = wp[1];
    #pragma unroll
    for (int r = 0; r < 32; r++) {
      const float4* ap = (const float4*)(A + r*FPK + kc*8);
      float4 a0 = ap[0], a1 = ap[1];
      acc[r] += w0.x*a0.x + w0.y*a0.y + w0.z*a0.z + w0.w*a0.w
              + w1.x*a1.x + w1.y*a1.y + w1.z*a1.z + w1.w*a1.w;
    }
  }
  #pragma unroll
  for (int r = 0; r < 32; r++) {
    int gr = base + r;
    if (gr < NPCD) H[gr*HD + o] = fmaxf(acc[r], 0.0f);
  }
}

// ---------------- FP layer 2: (5000x128)x(128->32), relu ----------------
__global__ void __launch_bounds__(256) fp2_kernel(const float* __restrict__ Hin,
                                                  const float* __restrict__ W,
                                                  const float* __restrict__ b,
                                                  float* __restrict__ fpf,
                                                  unsigned* __restrict__ gmax) {
  if (blockIdx.x == 0 && threadIdx.x == 0) *gmax = 0u;  // init for the gmax kernel that follows
  __shared__ float A[32*HD];
  int base = blockIdx.x*32, tid = threadIdx.x;
  for (int e = tid; e < 32*HD; e += 256) {
    int r = e >> 7; int gr = base + r;
    A[e] = (gr < NPCD) ? Hin[gr*HD + (e & 127)] : 0.0f;
  }
  __syncthreads();
  int o = tid & 31, rg = tid >> 5;
  float acc[4];
  #pragma unroll
  for (int j = 0; j < 4; j++) acc[j] = b[o];
  for (int kc = 0; kc < 16; kc++) {
    const float4* wp = (const float4*)(W + o*HD + kc*8);
    float4 w0 = wp[0], w1 = wp[1];
    #pragma unroll
    for (int j = 0; j < 4; j++) {
      int r = rg + (j << 3);
      const float4* ap = (const float4*)(A + r*HD + kc*8);
      float4 a0 = ap[0], a1 = ap[1];
      acc[j] += w0.x*a0.x + w0.y*a0.y + w0.z*a0.z + w0.w*a0.w
              + w1.x*a1.x + w1.y*a1.y + w1.z*a1.z + w1.w*a1.w;
    }
  }
  #pragma unroll
  for (int j = 0; j < 4; j++) {
    int gr = base + rg + (j << 3);
    if (gr < NPCD) fpf[gr*CPCD + o] = fmaxf(acc[j], 0.0f);
  }
}

// ---------------- global max of fp_feat (all >= 0) ----------------
__global__ void gmax_kernel(const float* __restrict__ fpf, unsigned* __restrict__ gmax) {
  int id = blockIdx.x*256 + threadIdx.x;
  float m = (id < NPCD*CPCD) ? fpf[id] : 0.0f;
  #pragma unroll
  for (int off = 1; off < 64; off <<= 1) m = fmaxf(m, __shfl_xor(m, off));
  if ((threadIdx.x & 63) == 0) atomicMax(gmax, __float_as_uint(m));
}

// ---------------- detection scores (wave per point) ----------------
__global__ void det_score_kernel(const float* __restrict__ fpf,
                                 const int* __restrict__ nbd,
                                 const unsigned* __restrict__ gmax,
                                 float* __restrict__ outs) {
  int wv = threadIdx.x >> 6, lane = threadIdx.x & 63;
  int i = blockIdx.x*4 + wv;
  float g = __uint_as_float(*gmax);
  float scale = 1.0f / (g + 1e-6f);
  int c = lane & 31, h = lane >> 5;
  float sum = 0.0f;
  const int* nbr = nbd + i*NBK + h*32;
  for (int k = 0; k < 32; k++) {
    int idx = nbr[k];
    sum += fpf[idx*CPCD + c];
  }
  sum += __shfl_xor(sum, 32);
  float mean = (sum * scale) * 0.015625f;   // /64 exact
  float fi = fpf[i*CPCD + c] * scale;
  float x = fi - mean;
  float lm = fmaxf(x, 0.0f) + log1pf(expf(-fabsf(x)));  // softplus = logaddexp(x,0)
  float dm = fi;
  #pragma unroll
  for (int off = 1; off < 64; off <<= 1) dm = fmaxf(dm, __shfl_xor(dm, off));
  float dw = fi / (1e-6f + dm);
  float pr = lm * dw;
  #pragma unroll
  for (int off = 1; off < 64; off <<= 1) pr = fmaxf(pr, __shfl_xor(pr, off));
  if (lane == 0) outs[i] = pr;
}

// ---------------- outputs: pcd_xyz copy + normalized vote_features ----------------
__global__ void vote_out_kernel(const float* __restrict__ pcd_xyz,
                                const float* __restrict__ fpf,
                                float* __restrict__ dout) {
  int id = blockIdx.x*256 + threadIdx.x;
  if (id < NPCD*3) dout[id] = pcd_xyz[id];
  int r = id - NPCD*3;
  if (r >= 0 && r < NPCD) {
    float ss = 0.0f;
    const float* fr = fpf + r*CPCD;
    #pragma unroll
    for (int cc = 0; cc < CPCD; cc++) ss += fr[cc]*fr[cc];
    float nrm = fmaxf(sqrtf(ss), 1e-12f);
    float* vf = dout + NPCD*3 + NPCD + r*CPCD;
    #pragma unroll
    for (int cc = 0; cc < CPCD; cc++) vf[cc] = fr[cc] / nrm;
  }
}

extern "C" void kernel_launch(void* const* d_in, const int* in_sizes, int n_in,
                              void* d_out, int out_size, void* d_ws, size_t ws_size,
                              hipStream_t stream) {
  const float* pcd_xyz      = (const float*)d_in[0];
  const float* pcd_features = (const float*)d_in[1];
  const float* rgb_xyz      = (const float*)d_in[2];
  const float* rgb_features = (const float*)d_in[3];
  const float* sa_W1 = (const float*)d_in[4];
  const float* sa_b1 = (const float*)d_in[5];
  const float* sa_W2 = (const float*)d_in[6];
  const float* sa_b2 = (const float*)d_in[7];
  const float* sa_W3 = (const float*)d_in[8];
  const float* sa_b3 = (const float*)d_in[9];
  const float* fp_W1 = (const float*)d_in[10];
  const float* fp_b1 = (const float*)d_in[11];
  const float* fp_W2 = (const float*)d_in[12];
  const float* fp_b2 = (const float*)d_in[13];
  float* out = (float*)d_out;

  float* xyz  = (float*)d_ws;            // 60000
  float* feat = xyz  + 60000;            // 3,200,000
  float* W1p  = feat + 3200000;          // 21,504
  float* axyz = W1p  + 21504;            // 12,288
  float* saf  = axyz + 12288;            // 524,288
  float* F    = saf  + 524288;           // 1,440,000
  float* Hb   = F    + 1440000;          // 640,000
  float* fpf  = Hb   + 640000;           // 160,000
  int*   fidx = (int*)(fpf + 160000);    // 4096
  int*   nbsa = fidx + 4096;             // 131,072
  int*   nbdet= nbsa + 131072;           // 320,000
  unsigned* gmaxp = (unsigned*)(nbdet + 320000);  // 1
  float* xsoa = (float*)(gmaxp + 1);     // 20480
  float* ysoa = xsoa + NSOA;             // 20480
  float* zsoa = ysoa + NSOA;             // 20480

  prep_kernel<<<2048, 256, 0, stream>>>(pcd_xyz, pcd_features, rgb_xyz, rgb_features,
                                        sa_W1, xyz, feat, W1p, xsoa, ysoa, zsoa);
  fps_kernel<<<1, 1024, 0, stream>>>(xsoa, ysoa, zsoa, fidx, axyz);
  sa_bq_kernel<<<1024, 256, 0, stream>>>(xyz, axyz, nbsa);
  sa_mlp_kernel<<<4096, 128, 0, stream>>>(xyz, feat, axyz, nbsa, W1p, sa_b1,
                                          sa_W2, sa_b2, sa_W3, sa_b3, saf);
  nn_interp_kernel<<<1250, 256, 0, stream>>>(xyz, feat, axyz, saf, F);
  fp1_kernel<<<157, 128, 0, stream>>>(F, fp_W1, fp_b1, Hb);
  fp2_kernel<<<157, 256, 0, stream>>>(Hb, fp_W2, fp_b2, fpf, gmaxp);
  det_bq_kernel<<<1250, 256, 0, stream>>>(pcd_xyz, nbdet);
  gmax_kernel<<<625, 256, 0, stream>>>(fpf, gmaxp);
  det_score_kernel<<<1250, 256, 0, stream>>>(fpf, nbdet, gmaxp, out + NPCD*3);
  vote_out_kernel<<<79, 256, 0, stream>>>(pcd_xyz, fpf, out);
}